// Round 13
// baseline (2215.511 us; speedup 1.0000x reference)
//
#include <hip/hip_runtime.h>
#include <stdint.h>

// LWTA MLP, decision/value-split.
//   presplit: x,W1 -> hi/lo bf16 arrays, XOR-swizzled 16B units (one-shot)
//   k1a v2 : dense split-bf16 MFMA GEMM, global_load_lds staging, dbuf LDS
//   k1c    : fp64 exact resolve of flagged L1 blocks
//   k2a    : sparse fp32 GEMM v7 (triple-buffer LDS, 2-deep counted prefetch,
//            raw lgkm-only barriers -> no vmcnt drain; T3/T4 recipe)
//   k2b    : fp64 resolve of flagged L2 blocks (recomputes h1 fp64)
//   k3     : sparse fp32 GEMM v7 -> dense out
// v7 rationale: v5 was at 66% of its 656us LDS-pipe floor; __syncthreads'
// vmcnt(0) drain + 1-tile prefetch left cold misses (~900cyc) stalling the
// LDS pipe. 2-deep named-reg prefetch (rule #20) + lgkm-only barriers fix it.
// Metadata TRANSPOSED [kblock][8192]. No __launch_bounds__ min-waves.

#define EPS1 3.0e-4f
#define EPS2 3.0e-5f
#define MST  8192L
#define SB   260

typedef __attribute__((ext_vector_type(8))) short bf16x8;
typedef __attribute__((ext_vector_type(4))) float f32x4;

#define GLD16(gp, lp) __builtin_amdgcn_global_load_lds( \
    (__attribute__((address_space(1))) const void*)(gp), \
    (__attribute__((address_space(3))) void*)(lp), 16, 0, 0)

// ---------------------------------------------------------------------------
// presplit: rows 0..8191 = x, 8192..12287 = W1. Per (row, kt): 32 f32 ->
// 64 shorts (hi units 0..3, lo units 4..7), unit u stored at (u ^ (row&7)).
__global__ __launch_bounds__(256)
void presplit(const float* __restrict__ x, const float* __restrict__ W1,
              short* __restrict__ Xsp, short* __restrict__ Wsp)
{
    const long tid = (long)blockIdx.x * 256 + threadIdx.x;  // 393216 total
    const int kt = (int)(tid & 31);
    const long row = tid >> 5;
    const float* src; short* dst; int key;
    if (row < 8192) {
        src = x + row * 1024 + kt * 32;
        dst = Xsp + (row * 32 + kt) * 64;
        key = (int)row & 7;
    } else {
        const long n = row - 8192;
        src = W1 + n * 1024 + kt * 32;
        dst = Wsp + (n * 32 + kt) * 64;
        key = (int)n & 7;
    }
    const float4* sp = (const float4*)src;
    float4 f4[8];
#pragma unroll
    for (int q = 0; q < 8; ++q) f4[q] = sp[q];

#pragma unroll
    for (int u = 0; u < 4; ++u) {
        const float4 a = f4[2 * u], b = f4[2 * u + 1];
        const float fv[8] = {a.x, a.y, a.z, a.w, b.x, b.y, b.z, b.w};
        unsigned hw[4], lw[4];
#pragma unroll
        for (int p = 0; p < 4; ++p) {
            const unsigned u0 = __float_as_uint(fv[2 * p]);
            const unsigned u1 = __float_as_uint(fv[2 * p + 1]);
            const float r0 = fv[2 * p]     - __uint_as_float(u0 & 0xFFFF0000u);
            const float r1 = fv[2 * p + 1] - __uint_as_float(u1 & 0xFFFF0000u);
            hw[p] = __builtin_amdgcn_perm(u1, u0, 0x07060302u);
            lw[p] = __builtin_amdgcn_perm(__float_as_uint(r1),
                                          __float_as_uint(r0), 0x07060302u);
        }
        uint4 hv = {hw[0], hw[1], hw[2], hw[3]};
        uint4 lv = {lw[0], lw[1], lw[2], lw[3]};
        *(uint4*)(dst + ((u ^ key) * 8))       = hv;
        *(uint4*)(dst + (((4 + u) ^ key) * 8)) = lv;
    }
}

// ---------------------------------------------------------------------------
// k1a v2: dense MFMA GEMM from pre-split arrays. 128j x 128m, BK=32, 256 thr.
__global__ __launch_bounds__(256)
void k1a_mfma_gload(const short* __restrict__ Wsp, const short* __restrict__ Xsp,
                    const float* __restrict__ bias,
                    float* __restrict__ vOut,
                    uint8_t* __restrict__ iOut, uint8_t* __restrict__ fOut)
{
    __shared__ __align__(16) short SM[2][2][128 * 64];   // 65536 B

    const int t = threadIdx.x;
    const int lane = t & 63;
    const int w = t >> 6;                 // wave 0..3
    const int g = lane >> 4, ml = lane & 15;
    const int sx = ml & 7;
    const long n0j = (long)blockIdx.x * 128;
    const long m0  = (long)blockIdx.y * 128;

    f32x4 acc[2][8];
#pragma unroll
    for (int jf = 0; jf < 2; ++jf)
#pragma unroll
        for (int mf = 0; mf < 8; ++mf) acc[jf][mf] = (f32x4){0.f, 0.f, 0.f, 0.f};

    const int srow = lane >> 3, sunit = lane & 7;

    auto issue = [&](int buf, int kt) {
#pragma unroll
        for (int i = 0; i < 4; ++i) {
            const int seg = w * 4 + i;
            const int row = seg * 8 + srow;
            const short* gA = Wsp + ((n0j + row) * 32L + kt) * 64 + sunit * 8;
            const short* gB = Xsp + ((m0  + row) * 32L + kt) * 64 + sunit * 8;
            GLD16(gA, &SM[buf][0][seg * 512]);
            GLD16(gB, &SM[buf][1][seg * 512]);
        }
    };

    issue(0, 0);
    asm volatile("s_waitcnt vmcnt(0)" ::: "memory");
    __syncthreads();

    for (int kt = 0; kt < 32; ++kt) {
        const int cur = kt & 1;
        if (kt + 1 < 32) issue(cur ^ 1, kt + 1);

        const short* As = &SM[cur][0][0];
        const short* Bs = &SM[cur][1][0];
        bf16x8 ahi[2], alo[2];
#pragma unroll
        for (int jf = 0; jf < 2; ++jf) {
            const int jr = w * 32 + jf * 16 + ml;
            ahi[jf] = *(const bf16x8*)&As[jr * 64 + ((g     ^ sx) * 8)];
            alo[jf] = *(const bf16x8*)&As[jr * 64 + (((4+g) ^ sx) * 8)];
        }
#pragma unroll
        for (int mf = 0; mf < 8; ++mf) {
            const int mr = mf * 16 + ml;
            const bf16x8 bhi = *(const bf16x8*)&Bs[mr * 64 + ((g     ^ sx) * 8)];
            const bf16x8 blo = *(const bf16x8*)&Bs[mr * 64 + (((4+g) ^ sx) * 8)];
#pragma unroll
            for (int jf = 0; jf < 2; ++jf) {
                acc[jf][mf] = __builtin_amdgcn_mfma_f32_16x16x32_bf16(
                    ahi[jf], bhi, acc[jf][mf], 0, 0, 0);
                acc[jf][mf] = __builtin_amdgcn_mfma_f32_16x16x32_bf16(
                    ahi[jf], blo, acc[jf][mf], 0, 0, 0);
                acc[jf][mf] = __builtin_amdgcn_mfma_f32_16x16x32_bf16(
                    alo[jf], bhi, acc[jf][mf], 0, 0, 0);
            }
        }
        asm volatile("s_waitcnt vmcnt(0)" ::: "memory");
        __syncthreads();
    }

#pragma unroll
    for (int jf = 0; jf < 2; ++jf) {
        const long jb = n0j + w * 32 + jf * 16;
        const float4 bs4 = *(const float4*)&bias[jb + g * 4];
        const float bsv[4] = {bs4.x, bs4.y, bs4.z, bs4.w};
        const long gblk = jb >> 4;
#pragma unroll
        for (int mf = 0; mf < 8; ++mf) {
            float v1 = -3.f, v2 = -3.f; int i1v = 0, bHi = 0;
#pragma unroll
            for (int reg = 0; reg < 4; ++reg) {
                const float pre = acc[jf][mf][reg] + bsv[reg];
                const float cv = fminf(fmaxf(pre, -1.f), 1.f);
                const int li = g * 4 + reg;
                if (cv > v1) { v2 = v1; v1 = cv; i1v = li; }
                else if (cv > v2) v2 = cv;
                bHi |= (pre > 1.f - EPS1 && pre < 1.f + EPS1) ? 1 : 0;
            }
#pragma unroll
            for (int mk = 16; mk <= 32; mk <<= 1) {
                const float ov1 = __shfl_xor(v1, mk);
                const int   oi1 = __shfl_xor(i1v, mk);
                const float ov2 = __shfl_xor(v2, mk);
                bHi |= __shfl_xor(bHi, mk);
                if (ov1 > v1 || (ov1 == v1 && oi1 < i1v)) {
                    v2 = fmaxf(v1, ov2); v1 = ov1; i1v = oi1;
                } else v2 = fmaxf(v2, ov1);
            }
            if (g == 0) {
                const bool stable = (v1 >= 1.f) && (v2 >= 1.f) && !bHi;
                const int unc = ((v1 - v2 <= EPS1) && !stable) || (v1 <= -1.f + EPS1);
                const long row = m0 + mf * 16 + ml;
                vOut[gblk * MST + row] = v1;
                iOut[gblk * MST + row] = (uint8_t)i1v;
                fOut[gblk * MST + row] = (uint8_t)unc;
            }
        }
    }
}

// ---------------------------------------------------------------------------
// k1c: fp64 resolve of flagged L1 blocks.
__global__ __launch_bounds__(256)
void k1_resolve(const float* __restrict__ A, const float* __restrict__ Bw,
                const float* __restrict__ bias, const uint8_t* __restrict__ fIn,
                uint8_t* __restrict__ iFix, float* __restrict__ vFix)
{
    const int gtid = blockIdx.x * 256 + threadIdx.x;
    const int wid = gtid >> 6, lane = gtid & 63;
    const long per = (256L * MST) / ((gridDim.x * 256) >> 6);
    const long s0 = (long)wid * per;
    for (long c = 0; c < per; c += 64) {
        unsigned long long mask = __ballot(fIn[s0 + c + lane] != 0);
        while (mask) {
            const int bit = __builtin_ctzll(mask); mask &= mask - 1;
            const long s = s0 + c + bit;
            const int blk = (int)(s >> 13); const long row = s & (MST - 1);
            const float4* xp = (const float4*)&A[row * 1024 + lane * 16];
            const float4 x0 = xp[0], x1 = xp[1], x2 = xp[2], x3 = xp[3];
            double best = -3.0; int bi = 0;
            for (int u = 0; u < 16; ++u) {
                const float4* wp = (const float4*)&Bw[(long)(blk * 16 + u) * 1024 + lane * 16];
                const float4 w0 = wp[0], w1 = wp[1], w2 = wp[2], w3 = wp[3];
                double su = (double)x0.x * w0.x + (double)x0.y * w0.y
                          + (double)x0.z * w0.z + (double)x0.w * w0.w
                          + (double)x1.x * w1.x + (double)x1.y * w1.y
                          + (double)x1.z * w1.z + (double)x1.w * w1.w
                          + (double)x2.x * w2.x + (double)x2.y * w2.y
                          + (double)x2.z * w2.z + (double)x2.w * w2.w
                          + (double)x3.x * w3.x + (double)x3.y * w3.y
                          + (double)x3.z * w3.z + (double)x3.w * w3.w;
#pragma unroll
                for (int off = 32; off; off >>= 1) su += __shfl_xor(su, off);
                const double xu = fmin(fmax(su + (double)bias[blk * 16 + u], -1.0), 1.0);
                if (xu > best) { best = xu; bi = u; }
            }
            if (lane == 0) { iFix[s] = (uint8_t)bi; vFix[s] = (float)best; }
        }
    }
}

// ---------------------------------------------------------------------------
// Sparse GEMM v7: BK=16, N_blk=256, 8 waves x 8 rows; TRIPLE-buffered LDS,
// 2-deep named-set prefetch, raw lgkm-only barriers (no vmcnt drain).
// Schedule per tile e: [bar] issue br(e+2) | compute(e) | issue meta(e+2) |
// write buf[(e+1)%3] <- br(e+1) (in flight ~2 tiles).
#define V7_BAR() do { \
    asm volatile("s_waitcnt lgkmcnt(0)" ::: "memory"); \
    __builtin_amdgcn_s_barrier(); \
    __builtin_amdgcn_sched_barrier(0); } while (0)

#define V7_TILE(SAb0, SAb1, SAva, SAia, SBb0, SBb1)                          \
  {                                                                          \
    V7_BAR();                                                                \
    const bool more2 = (e + 2 < nkt);                                        \
    if (more2) {                                                             \
        SAb0 = *(const float4*)(bsrc0 + (e + 2) * 16);                       \
        SAb1 = *(const float4*)(bsrc1 + (e + 2) * 16);                       \
    }                                                                        \
    const float* bb = &Bs[cur][0];                                           \
    _Pragma("unroll")                                                        \
    for (int r = 0; r < 8; ++r) {                                            \
        const float v = __uint_as_float(                                     \
            __builtin_amdgcn_readlane(__float_as_uint(SAva), r));            \
        const int kw = __builtin_amdgcn_readlane((int)SAia, r);              \
        const float4 b = *(const float4*)&bb[kw * SB + lane * 4];            \
        acc[r][0] += v * b.x; acc[r][1] += v * b.y;                          \
        acc[r][2] += v * b.z; acc[r][3] += v * b.w;                          \
    }                                                                        \
    if (more2) {                                                             \
        SAva = vA[(long)(e + 2) * MST + mrow];                               \
        SAia = iA[(long)(e + 2) * MST + mrow];                               \
    }                                                                        \
    const int nxt = (cur + 1 == 3) ? 0 : cur + 1;                            \
    if (e + 1 < nkt) {                                                       \
        Bs[nxt][bdst0 + 0*SB] = SBb0.x; Bs[nxt][bdst0 + 1*SB] = SBb0.y;      \
        Bs[nxt][bdst0 + 2*SB] = SBb0.z; Bs[nxt][bdst0 + 3*SB] = SBb0.w;      \
        Bs[nxt][bdst1 + 0*SB] = SBb1.x; Bs[nxt][bdst1 + 1*SB] = SBb1.y;      \
        Bs[nxt][bdst1 + 2*SB] = SBb1.z; Bs[nxt][bdst1 + 3*SB] = SBb1.w;      \
    }                                                                        \
    cur = nxt; ++e;                                                          \
  }

template<bool LWTA_OUT>
__global__ __launch_bounds__(512)
void sparse_gemm_v7(const float* __restrict__ vA, const uint8_t* __restrict__ iA,
                    const float* __restrict__ Bw, const float* __restrict__ bias,
                    int K, float eps,
                    float* __restrict__ vOut, uint8_t* __restrict__ iOut,
                    uint8_t* __restrict__ fOut, float* __restrict__ dOut, int N)
{
    __shared__ float Bs[3][16 * SB];   // 49,920 B
    const int t = threadIdx.x;
    const int lane = t & 63;
    const int w = t >> 6;
    const long m0 = (long)blockIdx.y * 64;
    const long n0 = (long)blockIdx.x * 256;
    const long rbase = m0 + w * 8;
    const int nkt = K / 16;            // 256 (even)

    float acc[8][4];
#pragma unroll
    for (int r = 0; r < 8; ++r)
#pragma unroll
        for (int d = 0; d < 4; ++d) acc[r][d] = 0.f;

    const int f0 = t, col0 = f0 >> 2, kq0 = (f0 & 3) * 4;
    const int f1 = 512 + t, col1 = f1 >> 2, kq1 = (f1 & 3) * 4;
    const float* bsrc0 = &Bw[(n0 + col0) * (long)K + kq0];
    const float* bsrc1 = &Bw[(n0 + col1) * (long)K + kq1];
    const int bdst0 = kq0 * SB + col0;
    const int bdst1 = kq1 * SB + col1;
    const long mrow = rbase + (lane & 7);

    // prologue: S0 = tile0, S1 = tile1; write buf0 from S0
    float4 s0b0 = *(const float4*)(bsrc0);
    float4 s0b1 = *(const float4*)(bsrc1);
    float    s0va = vA[mrow];
    unsigned s0ia = iA[mrow];
    float4 s1b0 = *(const float4*)(bsrc0 + 16);
    float4 s1b1 = *(const float4*)(bsrc1 + 16);
    float    s1va = vA[MST + mrow];
    unsigned s1ia = iA[MST + mrow];
    Bs[0][bdst0 + 0*SB] = s0b0.x; Bs[0][bdst0 + 1*SB] = s0b0.y;
    Bs[0][bdst0 + 2*SB] = s0b0.z; Bs[0][bdst0 + 3*SB] = s0b0.w;
    Bs[0][bdst1 + 0*SB] = s0b1.x; Bs[0][bdst1 + 1*SB] = s0b1.y;
    Bs[0][bdst1 + 2*SB] = s0b1.z; Bs[0][bdst1 + 3*SB] = s0b1.w;
    __syncthreads();

    int e = 0, cur = 0;
    while (e < nkt) {
        V7_TILE(s0b0, s0b1, s0va, s0ia, s1b0, s1b1);   // even tile: meta S0, write br S1
        V7_TILE(s1b0, s1b1, s1va, s1ia, s0b0, s0b1);   // odd tile: meta S1, write br S0
    }

    const float4 bv4 = *(const float4*)&bias[n0 + lane * 4];
    const float bias4[4] = {bv4.x, bv4.y, bv4.z, bv4.w};

    if (LWTA_OUT) {
#pragma unroll
        for (int r = 0; r < 8; ++r) {
            const long row = rbase + r;
            float v1 = -3.f, v2 = -3.f; int i1v = 0, bHi = 0;
#pragma unroll
            for (int d = 0; d < 4; ++d) {
                const float pre = acc[r][d] + bias4[d];
                const float cv = fminf(fmaxf(pre, -1.f), 1.f);
                const int li = (lane & 3) * 4 + d;
                if (cv > v1) { v2 = v1; v1 = cv; i1v = li; }
                else if (cv > v2) v2 = cv;
                bHi |= (pre > 1.f - eps && pre < 1.f + eps) ? 1 : 0;
            }
#pragma unroll
            for (int mk = 1; mk <= 2; mk <<= 1) {
                const float ov1 = __shfl_xor(v1, mk);
                const int   oi1 = __shfl_xor(i1v, mk);
                const float ov2 = __shfl_xor(v2, mk);
                bHi |= __shfl_xor(bHi, mk);
                if (ov1 > v1 || (ov1 == v1 && oi1 < i1v)) {
                    v2 = fmaxf(v1, ov2); v1 = ov1; i1v = oi1;
                } else v2 = fmaxf(v2, ov1);
            }
            if ((lane & 3) == 0) {
                const bool stable = (v1 >= 1.f) && (v2 >= 1.f) && !bHi;
                const int unc = ((v1 - v2 <= eps) && !stable) || (v1 <= -1.f + eps);
                const long blk = (n0 >> 4) + (lane >> 2);
                vOut[blk * MST + row] = v1;
                iOut[blk * MST + row] = (uint8_t)i1v;
                fOut[blk * MST + row] = (uint8_t)unc;
            }
        }
    } else {
#pragma unroll
        for (int r = 0; r < 8; ++r) {
            const long row = rbase + r;
            float4 o;
            o.x = acc[r][0] + bias4[0];
            o.y = acc[r][1] + bias4[1];
            o.z = acc[r][2] + bias4[2];
            o.w = acc[r][3] + bias4[3];
            *(float4*)&dOut[row * (long)N + n0 + lane * 4] = o;
        }
    }
}

// ---------------------------------------------------------------------------
// k2b: fp64 resolve of flagged L2 blocks (recomputes h1 fp64 on the fly).
__global__ __launch_bounds__(256)
void k2_resolve(const float* __restrict__ x, const float* __restrict__ W1,
                const float* __restrict__ b1, const uint8_t* __restrict__ iA,
                const float* __restrict__ W2r, const float* __restrict__ b2,
                const uint8_t* __restrict__ fIn, uint8_t* __restrict__ iFix,
                float* __restrict__ vFix)
{
    const int gtid = blockIdx.x * 256 + threadIdx.x;
    const int wid = gtid >> 6, lane = gtid & 63;
    const long per = (256L * MST) / ((gridDim.x * 256) >> 6);
    const long s0 = (long)wid * per;
    for (long c = 0; c < per; c += 64) {
        unsigned long long mask = __ballot(fIn[s0 + c + lane] != 0);
        while (mask) {
            const int bit = __builtin_ctzll(mask); mask &= mask - 1;
            const long s = s0 + c + bit;
            const int gblk = (int)(s >> 13); const long row = s & (MST - 1);

            const float4* xp = (const float4*)&x[row * 1024 + lane * 16];
            const float4 x0 = xp[0], x1 = xp[1], x2 = xp[2], x3 = xp[3];

            double hv[4]; int kp[4];
            for (int kq = 0; kq < 64; ++kq) {
#pragma unroll
                for (int j = 0; j < 4; ++j) {
                    const int kb = kq * 4 + j;
                    const int col = kb * 16 + (int)iA[(long)kb * MST + row];
                    const float4* wp = (const float4*)&W1[(long)col * 1024 + lane * 16];
                    const float4 w0 = wp[0], w1 = wp[1], w2 = wp[2], w3 = wp[3];
                    double p = (double)x0.x * w0.x + (double)x0.y * w0.y
                             + (double)x0.z * w0.z + (double)x0.w * w0.w
                             + (double)x1.x * w1.x + (double)x1.y * w1.y
                             + (double)x1.z * w1.z + (double)x1.w * w1.w
                             + (double)x2.x * w2.x + (double)x2.y * w2.y
                             + (double)x2.z * w2.z + (double)x2.w * w2.w
                             + (double)x3.x * w3.x + (double)x3.y * w3.y
                             + (double)x3.z * w3.z + (double)x3.w * w3.w;
#pragma unroll
                    for (int off = 32; off; off >>= 1) p += __shfl_xor(p, off);
                    if (lane == kq) {
                        hv[j] = fmin(fmax(p + (double)b1[col], -1.0), 1.0);
                        kp[j] = col;
                    }
                }
            }

            double best = -3.0; int bi = 0;
            for (int u = 0; u < 16; ++u) {
                const float* wr = &W2r[(long)(gblk * 16 + u) * 4096];
                double su = hv[0] * (double)wr[kp[0]] + hv[1] * (double)wr[kp[1]]
                          + hv[2] * (double)wr[kp[2]] + hv[3] * (double)wr[kp[3]];
#pragma unroll
                for (int off = 32; off; off >>= 1) su += __shfl_xor(su, off);
                const double xu = fmin(fmax(su + (double)b2[gblk * 16 + u], -1.0), 1.0);
                if (xu > best) { best = xu; bi = u; }
            }
            if (lane == 0) { iFix[s] = (uint8_t)bi; vFix[s] = (float)best; }
        }
    }
}

// ---------------------------------------------------------------------------
extern "C" void kernel_launch(void* const* d_in, const int* in_sizes, int n_in,
                              void* d_out, int out_size, void* d_ws, size_t ws_size,
                              hipStream_t stream)
{
    const float* x    = (const float*)d_in[0];
    const float* W1   = (const float*)d_in[1];
    const float* b1   = (const float*)d_in[2];
    const float* W2   = (const float*)d_in[3];
    const float* b2   = (const float*)d_in[4];
    const float* Wout = (const float*)d_in[5];
    const float* bout = (const float*)d_in[6];
    float* out = (float*)d_out;
    (void)in_sizes; (void)n_in; (void)out_size;

    const int B = 8192, Din = 1024, H = 4096, Dout = 1024;

    char* ws = (char*)d_ws;
    float*   v1f = (float*)ws;                        //  8 MB [256][8192]
    uint8_t* i1  = (uint8_t*)(ws + ( 8ll << 20));     //  2 MB
    uint8_t* f1  = (uint8_t*)(ws + (10ll << 20));     //  2 MB
    float*   v2f = (float*)(ws + (12ll << 20));       //  8 MB
    uint8_t* i2  = (uint8_t*)(ws + (20ll << 20));     //  2 MB
    uint8_t* f2  = (uint8_t*)(ws + (22ll << 20));     //  2 MB
    short*   Xsp = (short*)(ws + (24ll << 20));       // 32 MB [8192][32][64]
    short*   Wsp = (short*)(ws + (56ll << 20));       // 16 MB [4096][32][64]

    dim3 blk(256);
    const bool bigws = ws_size >= (72ll << 20);

    if (bigws) {
        presplit<<<1536, blk, 0, stream>>>(x, W1, Xsp, Wsp);
        k1a_mfma_gload<<<dim3(H / 128, B / 128), blk, 0, stream>>>(
            Wsp, Xsp, b1, v1f, i1, f1);
    } else {
        // (fallback path removed in r13: bigws held in rounds 11-12)
        presplit<<<1536, blk, 0, stream>>>(x, W1, Xsp, Wsp);
        k1a_mfma_gload<<<dim3(H / 128, B / 128), blk, 0, stream>>>(
            Wsp, Xsp, b1, v1f, i1, f1);
    }
    k1_resolve<<<4096, blk, 0, stream>>>(x, W1, b1, f1, i1, v1f);
    sparse_gemm_v7<true><<<dim3(H / 256, B / 64), dim3(512), 0, stream>>>(
        v1f, i1, W2, b2, H, EPS2, v2f, i2, f2, nullptr, H);
    k2_resolve<<<4096, blk, 0, stream>>>(x, W1, b1, i1, W2, b2, f2, i2, v2f);
    sparse_gemm_v7<false><<<dim3(Dout / 256, B / 64), dim3(512), 0, stream>>>(
        v2f, i2, Wout, bout, H, 0.f, nullptr, nullptr, nullptr, out, Dout);
}

// Round 14
// 1794.529 us; speedup vs baseline: 1.2346x; 1.2346x over previous
//
#include <hip/hip_runtime.h>
#include <stdint.h>

// LWTA MLP, decision/value-split.  [round-12 best config, v7 reverted]
//   presplit: x,W1 -> hi/lo bf16 arrays, XOR-swizzled 16B units (one-shot)
//   k1a v2 : dense split-bf16 MFMA GEMM, global_load_lds staging, dbuf LDS
//   k1c    : fp64 exact resolve of flagged L1 blocks
//   k2a    : sparse fp32 GEMM v5 (8 rows/wave, conflict-free gather)
//   k2b    : fp64 resolve of flagged L2 blocks (recomputes h1 fp64)
//   k3     : sparse fp32 GEMM v5 -> dense out
// History: v7 (3-buffer + pinned schedule) REGRESSED: VGPR 48->68, SGPR
// 48->112, occupancy 46->23%, FETCH 172->303MB (lost L2 reuse of W2).
// v5 at 983us = 1.5x of its 656us LDS-pipe floor is the plateau for this
// gather structure (occupancy/pipelining/metadata levers all falsified).
// Metadata TRANSPOSED [kblock][8192]. No __launch_bounds__ min-waves.

#define EPS1 3.0e-4f
#define EPS2 3.0e-5f
#define MST  8192L
#define SB   260

typedef __attribute__((ext_vector_type(8))) short bf16x8;
typedef __attribute__((ext_vector_type(4))) float f32x4;

#define GLD16(gp, lp) __builtin_amdgcn_global_load_lds( \
    (__attribute__((address_space(1))) const void*)(gp), \
    (__attribute__((address_space(3))) void*)(lp), 16, 0, 0)

// ---------------------------------------------------------------------------
// presplit: rows 0..8191 = x, 8192..12287 = W1. Per (row, kt): 32 f32 ->
// 64 shorts (hi units 0..3, lo units 4..7), unit u stored at (u ^ (row&7)).
__global__ __launch_bounds__(256)
void presplit(const float* __restrict__ x, const float* __restrict__ W1,
              short* __restrict__ Xsp, short* __restrict__ Wsp)
{
    const long tid = (long)blockIdx.x * 256 + threadIdx.x;  // 393216 total
    const int kt = (int)(tid & 31);
    const long row = tid >> 5;
    const float* src; short* dst; int key;
    if (row < 8192) {
        src = x + row * 1024 + kt * 32;
        dst = Xsp + (row * 32 + kt) * 64;
        key = (int)row & 7;
    } else {
        const long n = row - 8192;
        src = W1 + n * 1024 + kt * 32;
        dst = Wsp + (n * 32 + kt) * 64;
        key = (int)n & 7;
    }
    const float4* sp = (const float4*)src;
    float4 f4[8];
#pragma unroll
    for (int q = 0; q < 8; ++q) f4[q] = sp[q];

#pragma unroll
    for (int u = 0; u < 4; ++u) {
        const float4 a = f4[2 * u], b = f4[2 * u + 1];
        const float fv[8] = {a.x, a.y, a.z, a.w, b.x, b.y, b.z, b.w};
        unsigned hw[4], lw[4];
#pragma unroll
        for (int p = 0; p < 4; ++p) {
            const unsigned u0 = __float_as_uint(fv[2 * p]);
            const unsigned u1 = __float_as_uint(fv[2 * p + 1]);
            const float r0 = fv[2 * p]     - __uint_as_float(u0 & 0xFFFF0000u);
            const float r1 = fv[2 * p + 1] - __uint_as_float(u1 & 0xFFFF0000u);
            hw[p] = __builtin_amdgcn_perm(u1, u0, 0x07060302u);
            lw[p] = __builtin_amdgcn_perm(__float_as_uint(r1),
                                          __float_as_uint(r0), 0x07060302u);
        }
        uint4 hv = {hw[0], hw[1], hw[2], hw[3]};
        uint4 lv = {lw[0], lw[1], lw[2], lw[3]};
        *(uint4*)(dst + ((u ^ key) * 8))       = hv;
        *(uint4*)(dst + (((4 + u) ^ key) * 8)) = lv;
    }
}

// ---------------------------------------------------------------------------
// k1a v2: dense MFMA GEMM from pre-split arrays. 128j x 128m, BK=32, 256 thr.
__global__ __launch_bounds__(256)
void k1a_mfma_gload(const short* __restrict__ Wsp, const short* __restrict__ Xsp,
                    const float* __restrict__ bias,
                    float* __restrict__ vOut,
                    uint8_t* __restrict__ iOut, uint8_t* __restrict__ fOut)
{
    __shared__ __align__(16) short SM[2][2][128 * 64];   // 65536 B

    const int t = threadIdx.x;
    const int lane = t & 63;
    const int w = t >> 6;                 // wave 0..3
    const int g = lane >> 4, ml = lane & 15;
    const int sx = ml & 7;
    const long n0j = (long)blockIdx.x * 128;
    const long m0  = (long)blockIdx.y * 128;

    f32x4 acc[2][8];
#pragma unroll
    for (int jf = 0; jf < 2; ++jf)
#pragma unroll
        for (int mf = 0; mf < 8; ++mf) acc[jf][mf] = (f32x4){0.f, 0.f, 0.f, 0.f};

    const int srow = lane >> 3, sunit = lane & 7;

    auto issue = [&](int buf, int kt) {
#pragma unroll
        for (int i = 0; i < 4; ++i) {
            const int seg = w * 4 + i;
            const int row = seg * 8 + srow;
            const short* gA = Wsp + ((n0j + row) * 32L + kt) * 64 + sunit * 8;
            const short* gB = Xsp + ((m0  + row) * 32L + kt) * 64 + sunit * 8;
            GLD16(gA, &SM[buf][0][seg * 512]);
            GLD16(gB, &SM[buf][1][seg * 512]);
        }
    };

    issue(0, 0);
    asm volatile("s_waitcnt vmcnt(0)" ::: "memory");
    __syncthreads();

    for (int kt = 0; kt < 32; ++kt) {
        const int cur = kt & 1;
        if (kt + 1 < 32) issue(cur ^ 1, kt + 1);

        const short* As = &SM[cur][0][0];
        const short* Bs = &SM[cur][1][0];
        bf16x8 ahi[2], alo[2];
#pragma unroll
        for (int jf = 0; jf < 2; ++jf) {
            const int jr = w * 32 + jf * 16 + ml;
            ahi[jf] = *(const bf16x8*)&As[jr * 64 + ((g     ^ sx) * 8)];
            alo[jf] = *(const bf16x8*)&As[jr * 64 + (((4+g) ^ sx) * 8)];
        }
#pragma unroll
        for (int mf = 0; mf < 8; ++mf) {
            const int mr = mf * 16 + ml;
            const bf16x8 bhi = *(const bf16x8*)&Bs[mr * 64 + ((g     ^ sx) * 8)];
            const bf16x8 blo = *(const bf16x8*)&Bs[mr * 64 + (((4+g) ^ sx) * 8)];
#pragma unroll
            for (int jf = 0; jf < 2; ++jf) {
                acc[jf][mf] = __builtin_amdgcn_mfma_f32_16x16x32_bf16(
                    ahi[jf], bhi, acc[jf][mf], 0, 0, 0);
                acc[jf][mf] = __builtin_amdgcn_mfma_f32_16x16x32_bf16(
                    ahi[jf], blo, acc[jf][mf], 0, 0, 0);
                acc[jf][mf] = __builtin_amdgcn_mfma_f32_16x16x32_bf16(
                    alo[jf], bhi, acc[jf][mf], 0, 0, 0);
            }
        }
        asm volatile("s_waitcnt vmcnt(0)" ::: "memory");
        __syncthreads();
    }

#pragma unroll
    for (int jf = 0; jf < 2; ++jf) {
        const long jb = n0j + w * 32 + jf * 16;
        const float4 bs4 = *(const float4*)&bias[jb + g * 4];
        const float bsv[4] = {bs4.x, bs4.y, bs4.z, bs4.w};
        const long gblk = jb >> 4;
#pragma unroll
        for (int mf = 0; mf < 8; ++mf) {
            float v1 = -3.f, v2 = -3.f; int i1v = 0, bHi = 0;
#pragma unroll
            for (int reg = 0; reg < 4; ++reg) {
                const float pre = acc[jf][mf][reg] + bsv[reg];
                const float cv = fminf(fmaxf(pre, -1.f), 1.f);
                const int li = g * 4 + reg;
                if (cv > v1) { v2 = v1; v1 = cv; i1v = li; }
                else if (cv > v2) v2 = cv;
                bHi |= (pre > 1.f - EPS1 && pre < 1.f + EPS1) ? 1 : 0;
            }
#pragma unroll
            for (int mk = 16; mk <= 32; mk <<= 1) {
                const float ov1 = __shfl_xor(v1, mk);
                const int   oi1 = __shfl_xor(i1v, mk);
                const float ov2 = __shfl_xor(v2, mk);
                bHi |= __shfl_xor(bHi, mk);
                if (ov1 > v1 || (ov1 == v1 && oi1 < i1v)) {
                    v2 = fmaxf(v1, ov2); v1 = ov1; i1v = oi1;
                } else v2 = fmaxf(v2, ov1);
            }
            if (g == 0) {
                const bool stable = (v1 >= 1.f) && (v2 >= 1.f) && !bHi;
                const int unc = ((v1 - v2 <= EPS1) && !stable) || (v1 <= -1.f + EPS1);
                const long row = m0 + mf * 16 + ml;
                vOut[gblk * MST + row] = v1;
                iOut[gblk * MST + row] = (uint8_t)i1v;
                fOut[gblk * MST + row] = (uint8_t)unc;
            }
        }
    }
}

// ---------------------------------------------------------------------------
// k1c: fp64 resolve of flagged L1 blocks.
__global__ __launch_bounds__(256)
void k1_resolve(const float* __restrict__ A, const float* __restrict__ Bw,
                const float* __restrict__ bias, const uint8_t* __restrict__ fIn,
                uint8_t* __restrict__ iFix, float* __restrict__ vFix)
{
    const int gtid = blockIdx.x * 256 + threadIdx.x;
    const int wid = gtid >> 6, lane = gtid & 63;
    const long per = (256L * MST) / ((gridDim.x * 256) >> 6);
    const long s0 = (long)wid * per;
    for (long c = 0; c < per; c += 64) {
        unsigned long long mask = __ballot(fIn[s0 + c + lane] != 0);
        while (mask) {
            const int bit = __builtin_ctzll(mask); mask &= mask - 1;
            const long s = s0 + c + bit;
            const int blk = (int)(s >> 13); const long row = s & (MST - 1);
            const float4* xp = (const float4*)&A[row * 1024 + lane * 16];
            const float4 x0 = xp[0], x1 = xp[1], x2 = xp[2], x3 = xp[3];
            double best = -3.0; int bi = 0;
            for (int u = 0; u < 16; ++u) {
                const float4* wp = (const float4*)&Bw[(long)(blk * 16 + u) * 1024 + lane * 16];
                const float4 w0 = wp[0], w1 = wp[1], w2 = wp[2], w3 = wp[3];
                double su = (double)x0.x * w0.x + (double)x0.y * w0.y
                          + (double)x0.z * w0.z + (double)x0.w * w0.w
                          + (double)x1.x * w1.x + (double)x1.y * w1.y
                          + (double)x1.z * w1.z + (double)x1.w * w1.w
                          + (double)x2.x * w2.x + (double)x2.y * w2.y
                          + (double)x2.z * w2.z + (double)x2.w * w2.w
                          + (double)x3.x * w3.x + (double)x3.y * w3.y
                          + (double)x3.z * w3.z + (double)x3.w * w3.w;
#pragma unroll
                for (int off = 32; off; off >>= 1) su += __shfl_xor(su, off);
                const double xu = fmin(fmax(su + (double)bias[blk * 16 + u], -1.0), 1.0);
                if (xu > best) { best = xu; bi = u; }
            }
            if (lane == 0) { iFix[s] = (uint8_t)bi; vFix[s] = (float)best; }
        }
    }
}

// ---------------------------------------------------------------------------
// Sparse GEMM v5 (round-10/12 best): BK=16, N_blk=256, 8 waves x 8 rows.
// Winner (v,kw) wave-uniform via readlane; gather = contiguous 1KB
// ds_read_b128. Double-buffered LDS (33 KB), single barrier per k-tile.
template<bool LWTA_OUT>
__global__ __launch_bounds__(512)
void sparse_gemm_v5(const float* __restrict__ vA, const uint8_t* __restrict__ iA,
                    const float* __restrict__ Bw, const float* __restrict__ bias,
                    int K, float eps,
                    float* __restrict__ vOut, uint8_t* __restrict__ iOut,
                    uint8_t* __restrict__ fOut, float* __restrict__ dOut, int N)
{
    __shared__ float Bs[2][16 * SB];
    const int t = threadIdx.x;
    const int lane = t & 63;
    const int w = t >> 6;
    const long m0 = (long)blockIdx.y * 64;
    const long n0 = (long)blockIdx.x * 256;
    const long rbase = m0 + w * 8;
    const int nkt = K / 16;

    float acc[8][4];
#pragma unroll
    for (int r = 0; r < 8; ++r)
#pragma unroll
        for (int d = 0; d < 4; ++d) acc[r][d] = 0.f;

    const float* bsrc[2]; int bdst[2];
#pragma unroll
    for (int i = 0; i < 2; ++i) {
        const int f = i * 512 + t, col = f >> 2, kq = (f & 3) * 4;
        bsrc[i] = &Bw[(n0 + col) * (long)K + kq];
        bdst[i] = kq * SB + col;
    }
    const long mrow = rbase + (lane & 7);

    float4 br[2];
#pragma unroll
    for (int i = 0; i < 2; ++i) br[i] = *(const float4*)(bsrc[i]);
    float    va = vA[mrow];
    unsigned ia = iA[mrow];
#pragma unroll
    for (int i = 0; i < 2; ++i) {
        Bs[0][bdst[i] + 0*SB] = br[i].x; Bs[0][bdst[i] + 1*SB] = br[i].y;
        Bs[0][bdst[i] + 2*SB] = br[i].z; Bs[0][bdst[i] + 3*SB] = br[i].w;
    }

    for (int kt = 0; kt < nkt; ++kt) {
        __syncthreads();
        const int cur = kt & 1;
        const bool more = kt + 1 < nkt;
        float nva = 0.f; unsigned nia = 0;
        if (more) {
            const int k0n = (kt + 1) * 16;
#pragma unroll
            for (int i = 0; i < 2; ++i) br[i] = *(const float4*)(bsrc[i] + k0n);
            nva = vA[(long)(kt + 1) * MST + mrow];
            nia = iA[(long)(kt + 1) * MST + mrow];
        }
        const float* bb = &Bs[cur][0];
#pragma unroll
        for (int r = 0; r < 8; ++r) {
            const float v = __uint_as_float(
                __builtin_amdgcn_readlane(__float_as_uint(va), r));
            const int kw = __builtin_amdgcn_readlane((int)ia, r);
            const float4 b = *(const float4*)&bb[kw * SB + lane * 4];
            acc[r][0] += v * b.x; acc[r][1] += v * b.y;
            acc[r][2] += v * b.z; acc[r][3] += v * b.w;
        }
        if (more) {
            const int nxt = cur ^ 1;
#pragma unroll
            for (int i = 0; i < 2; ++i) {
                Bs[nxt][bdst[i] + 0*SB] = br[i].x; Bs[nxt][bdst[i] + 1*SB] = br[i].y;
                Bs[nxt][bdst[i] + 2*SB] = br[i].z; Bs[nxt][bdst[i] + 3*SB] = br[i].w;
            }
            va = nva; ia = nia;
        }
    }

    const float4 bv4 = *(const float4*)&bias[n0 + lane * 4];
    const float bias4[4] = {bv4.x, bv4.y, bv4.z, bv4.w};

    if (LWTA_OUT) {
#pragma unroll
        for (int r = 0; r < 8; ++r) {
            const long row = rbase + r;
            float v1 = -3.f, v2 = -3.f; int i1v = 0, bHi = 0;
#pragma unroll
            for (int d = 0; d < 4; ++d) {
                const float pre = acc[r][d] + bias4[d];
                const float cv = fminf(fmaxf(pre, -1.f), 1.f);
                const int li = (lane & 3) * 4 + d;
                if (cv > v1) { v2 = v1; v1 = cv; i1v = li; }
                else if (cv > v2) v2 = cv;
                bHi |= (pre > 1.f - eps && pre < 1.f + eps) ? 1 : 0;
            }
#pragma unroll
            for (int mk = 1; mk <= 2; mk <<= 1) {
                const float ov1 = __shfl_xor(v1, mk);
                const int   oi1 = __shfl_xor(i1v, mk);
                const float ov2 = __shfl_xor(v2, mk);
                bHi |= __shfl_xor(bHi, mk);
                if (ov1 > v1 || (ov1 == v1 && oi1 < i1v)) {
                    v2 = fmaxf(v1, ov2); v1 = ov1; i1v = oi1;
                } else v2 = fmaxf(v2, ov1);
            }
            if ((lane & 3) == 0) {
                const bool stable = (v1 >= 1.f) && (v2 >= 1.f) && !bHi;
                const int unc = ((v1 - v2 <= eps) && !stable) || (v1 <= -1.f + eps);
                const long blk = (n0 >> 4) + (lane >> 2);
                vOut[blk * MST + row] = v1;
                iOut[blk * MST + row] = (uint8_t)i1v;
                fOut[blk * MST + row] = (uint8_t)unc;
            }
        }
    } else {
#pragma unroll
        for (int r = 0; r < 8; ++r) {
            const long row = rbase + r;
            float4 o;
            o.x = acc[r][0] + bias4[0];
            o.y = acc[r][1] + bias4[1];
            o.z = acc[r][2] + bias4[2];
            o.w = acc[r][3] + bias4[3];
            *(float4*)&dOut[row * (long)N + n0 + lane * 4] = o;
        }
    }
}

// ---------------------------------------------------------------------------
// k2b: fp64 resolve of flagged L2 blocks (recomputes h1 fp64 on the fly).
__global__ __launch_bounds__(256)
void k2_resolve(const float* __restrict__ x, const float* __restrict__ W1,
                const float* __restrict__ b1, const uint8_t* __restrict__ iA,
                const float* __restrict__ W2r, const float* __restrict__ b2,
                const uint8_t* __restrict__ fIn, uint8_t* __restrict__ iFix,
                float* __restrict__ vFix)
{
    const int gtid = blockIdx.x * 256 + threadIdx.x;
    const int wid = gtid >> 6, lane = gtid & 63;
    const long per = (256L * MST) / ((gridDim.x * 256) >> 6);
    const long s0 = (long)wid * per;
    for (long c = 0; c < per; c += 64) {
        unsigned long long mask = __ballot(fIn[s0 + c + lane] != 0);
        while (mask) {
            const int bit = __builtin_ctzll(mask); mask &= mask - 1;
            const long s = s0 + c + bit;
            const int gblk = (int)(s >> 13); const long row = s & (MST - 1);

            const float4* xp = (const float4*)&x[row * 1024 + lane * 16];
            const float4 x0 = xp[0], x1 = xp[1], x2 = xp[2], x3 = xp[3];

            double hv[4]; int kp[4];
            for (int kq = 0; kq < 64; ++kq) {
#pragma unroll
                for (int j = 0; j < 4; ++j) {
                    const int kb = kq * 4 + j;
                    const int col = kb * 16 + (int)iA[(long)kb * MST + row];
                    const float4* wp = (const float4*)&W1[(long)col * 1024 + lane * 16];
                    const float4 w0 = wp[0], w1 = wp[1], w2 = wp[2], w3 = wp[3];
                    double p = (double)x0.x * w0.x + (double)x0.y * w0.y
                             + (double)x0.z * w0.z + (double)x0.w * w0.w
                             + (double)x1.x * w1.x + (double)x1.y * w1.y
                             + (double)x1.z * w1.z + (double)x1.w * w1.w
                             + (double)x2.x * w2.x + (double)x2.y * w2.y
                             + (double)x2.z * w2.z + (double)x2.w * w2.w
                             + (double)x3.x * w3.x + (double)x3.y * w3.y
                             + (double)x3.z * w3.z + (double)x3.w * w3.w;
#pragma unroll
                    for (int off = 32; off; off >>= 1) p += __shfl_xor(p, off);
                    if (lane == kq) {
                        hv[j] = fmin(fmax(p + (double)b1[col], -1.0), 1.0);
                        kp[j] = col;
                    }
                }
            }

            double best = -3.0; int bi = 0;
            for (int u = 0; u < 16; ++u) {
                const float* wr = &W2r[(long)(gblk * 16 + u) * 4096];
                double su = hv[0] * (double)wr[kp[0]] + hv[1] * (double)wr[kp[1]]
                          + hv[2] * (double)wr[kp[2]] + hv[3] * (double)wr[kp[3]];
#pragma unroll
                for (int off = 32; off; off >>= 1) su += __shfl_xor(su, off);
                const double xu = fmin(fmax(su + (double)b2[gblk * 16 + u], -1.0), 1.0);
                if (xu > best) { best = xu; bi = u; }
            }
            if (lane == 0) { iFix[s] = (uint8_t)bi; vFix[s] = (float)best; }
        }
    }
}

// ---------------------------------------------------------------------------
extern "C" void kernel_launch(void* const* d_in, const int* in_sizes, int n_in,
                              void* d_out, int out_size, void* d_ws, size_t ws_size,
                              hipStream_t stream)
{
    const float* x    = (const float*)d_in[0];
    const float* W1   = (const float*)d_in[1];
    const float* b1   = (const float*)d_in[2];
    const float* W2   = (const float*)d_in[3];
    const float* b2   = (const float*)d_in[4];
    const float* Wout = (const float*)d_in[5];
    const float* bout = (const float*)d_in[6];
    float* out = (float*)d_out;
    (void)in_sizes; (void)n_in; (void)out_size; (void)ws_size;

    const int B = 8192, Din = 1024, H = 4096, Dout = 1024;

    char* ws = (char*)d_ws;
    float*   v1f = (float*)ws;                        //  8 MB [256][8192]
    uint8_t* i1  = (uint8_t*)(ws + ( 8ll << 20));     //  2 MB
    uint8_t* f1  = (uint8_t*)(ws + (10ll << 20));     //  2 MB
    float*   v2f = (float*)(ws + (12ll << 20));       //  8 MB
    uint8_t* i2  = (uint8_t*)(ws + (20ll << 20));     //  2 MB
    uint8_t* f2  = (uint8_t*)(ws + (22ll << 20));     //  2 MB
    short*   Xsp = (short*)(ws + (24ll << 20));       // 32 MB [8192][32][64]
    short*   Wsp = (short*)(ws + (56ll << 20));       // 16 MB [4096][32][64]

    dim3 blk(256);
    presplit<<<1536, blk, 0, stream>>>(x, W1, Xsp, Wsp);
    k1a_mfma_gload<<<dim3(H / 128, B / 128), blk, 0, stream>>>(
        Wsp, Xsp, b1, v1f, i1, f1);
    k1_resolve<<<4096, blk, 0, stream>>>(x, W1, b1, f1, i1, v1f);
    sparse_gemm_v5<true><<<dim3(H / 256, B / 64), dim3(512), 0, stream>>>(
        v1f, i1, W2, b2, H, EPS2, v2f, i2, f2, nullptr, H);
    k2_resolve<<<4096, blk, 0, stream>>>(x, W1, b1, i1, W2, b2, f2, i2, v2f);
    sparse_gemm_v5<false><<<dim3(Dout / 256, B / 64), dim3(512), 0, stream>>>(
        v2f, i2, Wout, bout, H, 0.f, nullptr, nullptr, nullptr, out, Dout);
}